// Round 1
// baseline (657.061 us; speedup 1.0000x reference)
//
#include <hip/hip_runtime.h>
#include <hip/hip_bf16.h>
#include <stdint.h>

typedef __attribute__((ext_vector_type(8))) short short8;
typedef __attribute__((ext_vector_type(4))) float f32x4;
typedef __attribute__((ext_vector_type(4))) unsigned short us4;

#define SEQ_L 2048
#define NHEADS 16
#define HD 64
#define DMODEL 1024
#define NB 4

__device__ __forceinline__ short f2bf(float f) {
  unsigned int x = __float_as_uint(f);
  x += 0x7fffu + ((x >> 16) & 1u);   // RNE
  return (short)(x >> 16);
}

__device__ __forceinline__ void gload16(const void* g, void* l) {
  __builtin_amdgcn_global_load_lds(
      (const __attribute__((address_space(1))) unsigned char*)g,
      (__attribute__((address_space(3))) unsigned char*)l, 16, 0, 0);
}

// ---------------- fp32 -> bf16 conversion (memory-bound, vectorized) --------
__global__ void f32_to_bf16_kernel(const float* __restrict__ src,
                                   short* __restrict__ dst, int n) {
  int i = (blockIdx.x * 256 + threadIdx.x) * 4;
  if (i + 3 >= n + 1) { if (i >= n) return; }
  float4 f = *reinterpret_cast<const float4*>(src + i);
  us4 o;
  o[0] = (unsigned short)f2bf(f.x);
  o[1] = (unsigned short)f2bf(f.y);
  o[2] = (unsigned short)f2bf(f.z);
  o[3] = (unsigned short)f2bf(f.w);
  *reinterpret_cast<us4*>(dst + i) = o;
}

// ---------------- GEMM: C[M,N] = A[M,K] * W[N,K]^T  (both K-major) ----------
// m97 structure: 128x128 tile, BK=32, 4 waves (2x2), global_load_lds w=16,
// double-buffered LDS, 2-phase.
// EPI 0: bf16 out, per-head layout [B,H,L,64], value = (acc+bias)*oscale
// EPI 1: fp32 out, row-major [M,DMODEL], value = acc+bias
template <int EPI>
__global__ void gemm_bt(const short* __restrict__ A, const short* __restrict__ W,
                        const float* __restrict__ bias, void* __restrict__ Cout,
                        int K, float oscale) {
  const int tid = threadIdx.x;
  const int w = tid >> 6, l = tid & 63;
  const int tm = blockIdx.x * 128;
  const int tn = blockIdx.y * 128;
  const int wm = (w >> 1) * 64, wn = (w & 1) * 64;
  __shared__ short As[2][128 * 32];
  __shared__ short Bs[2][128 * 32];

  // staging: wave w owns chunks {2w, 2w+1} of each 8KB tile
  const int srow = w * 32 + (l >> 2);
  const int scol = (l & 3) * 8;
  const short* pa0 = A + (size_t)(tm + srow) * K + scol;
  const short* pa1 = pa0 + (size_t)16 * K;
  const short* pb0 = W + (size_t)(tn + srow) * K + scol;
  const short* pb1 = pb0 + (size_t)16 * K;
  const int ldst = w * 1024 + l * 8;

  gload16(pa0, &As[0][ldst]);
  gload16(pa1, &As[0][ldst + 512]);
  gload16(pb0, &Bs[0][ldst]);
  gload16(pb1, &Bs[0][ldst + 512]);

  f32x4 acc[4][4];
#pragma unroll
  for (int i = 0; i < 4; ++i)
#pragma unroll
    for (int j = 0; j < 4; ++j) acc[i][j] = (f32x4){0.f, 0.f, 0.f, 0.f};

  const int lr = l >> 4, lc = l & 15;
  const int nt = K / 32;
  int cur = 0;
  __syncthreads();
  for (int t = 0; t < nt; ++t) {
    if (t + 1 < nt) {
      int ko = (t + 1) * 32;
      gload16(pa0 + ko, &As[cur ^ 1][ldst]);
      gload16(pa1 + ko, &As[cur ^ 1][ldst + 512]);
      gload16(pb0 + ko, &Bs[cur ^ 1][ldst]);
      gload16(pb1 + ko, &Bs[cur ^ 1][ldst + 512]);
    }
    short8 af[4], bfv[4];
#pragma unroll
    for (int i = 0; i < 4; ++i)
      af[i] = *reinterpret_cast<const short8*>(
          &As[cur][(wm + i * 16 + lc) * 32 + lr * 8]);
#pragma unroll
    for (int j = 0; j < 4; ++j)
      bfv[j] = *reinterpret_cast<const short8*>(
          &Bs[cur][(wn + j * 16 + lc) * 32 + lr * 8]);
#pragma unroll
    for (int i = 0; i < 4; ++i)
#pragma unroll
      for (int j = 0; j < 4; ++j)
        acc[i][j] =
            __builtin_amdgcn_mfma_f32_16x16x32_bf16(af[i], bfv[j], acc[i][j], 0, 0, 0);
    __syncthreads();
    cur ^= 1;
  }

  if (EPI == 0) {
    short* O = (short*)Cout;
#pragma unroll
    for (int j = 0; j < 4; ++j) {
      int col = tn + wn + j * 16 + lc;
      float bv = bias[col];
      int h = col >> 6, d = col & 63;
#pragma unroll
      for (int i = 0; i < 4; ++i)
#pragma unroll
        for (int r = 0; r < 4; ++r) {
          int row = tm + wm + i * 16 + lr * 4 + r;
          int b = row >> 11, pos = row & 2047;
          float v = (acc[i][j][r] + bv) * oscale;
          O[(((size_t)(b * NHEADS + h) * SEQ_L + pos) << 6) + d] = f2bf(v);
        }
    }
  } else {
    float* O = (float*)Cout;
#pragma unroll
    for (int j = 0; j < 4; ++j) {
      int col = tn + wn + j * 16 + lc;
      float bv = bias[col];
#pragma unroll
      for (int i = 0; i < 4; ++i)
#pragma unroll
        for (int r = 0; r < 4; ++r) {
          int row = tm + wm + i * 16 + lr * 4 + r;
          O[(size_t)row * DMODEL + col] = acc[i][j][r] + bv;
        }
    }
  }
}

// ---------------- flash attention -------------------------------------------
// grid (16 q-tiles, 64 b*h). 4 waves, QBLK=128 (32 rows/wave), KBLK=64.
// All LDS tiles have 128B rows -> XOR swizzle e ^= (row&7)<<3 (elements).
__global__ void attn_fwd(const short* __restrict__ Qh, const short* __restrict__ Kh,
                         const short* __restrict__ Vh, const int* __restrict__ mask,
                         short* __restrict__ O) {
  const int tid = threadIdx.x;
  const int w = tid >> 6, l = tid & 63;
  const int qt = blockIdx.x;
  const int bh = blockIdx.y;
  const int b = bh >> 4, h = bh & 15;
  const short* q = Qh + (size_t)bh * SEQ_L * HD;
  const short* k = Kh + (size_t)bh * SEQ_L * HD;
  const short* v = Vh + (size_t)bh * SEQ_L * HD;
  const int* mrow = mask + b * SEQ_L;
  const int qbase = qt * 128;

  __shared__ short QP[128 * 64];  // Q fragments source, then P tile
  __shared__ short KT[64 * 64];
  __shared__ short VT[64 * 64];   // V^T : [d][k]

  auto sw = [](int row, int e) { return row * 64 + (e ^ ((row & 7) << 3)); };

  // stage Q via global_load_lds: linear dest, inverse-swizzled source
#pragma unroll
  for (int qi = 0; qi < 4; ++qi) {
    int c = w * 4 + qi;
    int row = c * 8 + (l >> 3);
    int ss = (l & 7) ^ (l >> 3);
    gload16(q + (size_t)(qbase + row) * HD + ss * 8, &QP[c * 512 + l * 8]);
  }
  __syncthreads();

  const int lr = l >> 4, lc = l & 15;
  short8 qf[2][2];
#pragma unroll
  for (int i = 0; i < 2; ++i)
#pragma unroll
    for (int s = 0; s < 2; ++s)
      qf[i][s] = *reinterpret_cast<const short8*>(
          &QP[sw(w * 32 + i * 16 + lc, s * 32 + lr * 8)]);

  float m_st[2][4], l_st[2][4];
  f32x4 acc_o[2][4];
#pragma unroll
  for (int i = 0; i < 2; ++i)
#pragma unroll
    for (int r = 0; r < 4; ++r) { m_st[i][r] = -__builtin_inff(); l_st[i][r] = 0.f; }
#pragma unroll
  for (int i = 0; i < 2; ++i)
#pragma unroll
    for (int j = 0; j < 4; ++j) acc_o[i][j] = (f32x4){0.f, 0.f, 0.f, 0.f};

  for (int ic = 0; ic < SEQ_L / 64; ++ic) {
    const int kb = ic * 64;
    // stage K tile (swizzled source, linear dest)
#pragma unroll
    for (int qi = 0; qi < 2; ++qi) {
      int c = w * 2 + qi;
      int row = c * 8 + (l >> 3);
      int ss = (l & 7) ^ (l >> 3);
      gload16(k + (size_t)(kb + row) * HD + ss * 8, &KT[c * 512 + l * 8]);
    }
    // stage V^T via register transpose (swizzled scalar writes, conflict-free)
    {
      const short* vp = v + (size_t)(kb + l) * HD + w * 16;
      short8 v0 = *reinterpret_cast<const short8*>(vp);
      short8 v1 = *reinterpret_cast<const short8*>(vp + 8);
#pragma unroll
      for (int e = 0; e < 8; ++e) {
        VT[sw(w * 16 + e, l)] = v0[e];
        VT[sw(w * 16 + 8 + e, l)] = v1[e];
      }
    }
    __syncthreads();

    // S = Q K^T (1/sqrt(hd) folded into Q at projection)
    f32x4 s_acc[2][4];
#pragma unroll
    for (int i = 0; i < 2; ++i)
#pragma unroll
      for (int j = 0; j < 4; ++j) s_acc[i][j] = (f32x4){0.f, 0.f, 0.f, 0.f};
#pragma unroll
    for (int s = 0; s < 2; ++s) {
      short8 kf[4];
#pragma unroll
      for (int j = 0; j < 4; ++j)
        kf[j] = *reinterpret_cast<const short8*>(
            &KT[sw(j * 16 + lc, s * 32 + lr * 8)]);
#pragma unroll
      for (int i = 0; i < 2; ++i)
#pragma unroll
        for (int j = 0; j < 4; ++j)
          s_acc[i][j] =
              __builtin_amdgcn_mfma_f32_16x16x32_bf16(qf[i][s], kf[j], s_acc[i][j], 0, 0, 0);
    }

    int mk[4];
#pragma unroll
    for (int j = 0; j < 4; ++j) mk[j] = mrow[kb + j * 16 + lc];

    // online softmax (rows live in 16-lane groups; shfl_xor 1/2/4/8)
    float mnew[2][4], sc[2][4], ps[2][4];
#pragma unroll
    for (int i = 0; i < 2; ++i)
#pragma unroll
      for (int r = 0; r < 4; ++r) {
        float mx = -__builtin_inff();
#pragma unroll
        for (int j = 0; j < 4; ++j) {
          float sv = mk[j] ? s_acc[i][j][r] : -__builtin_inff();
          mx = fmaxf(mx, sv);
        }
        for (int d = 1; d < 16; d <<= 1) mx = fmaxf(mx, __shfl_xor(mx, d, 64));
        mx = fmaxf(mx, m_st[i][r]);
        sc[i][r] = (m_st[i][r] == mx) ? 1.f : __expf(m_st[i][r] - mx);
        mnew[i][r] = mx;
        m_st[i][r] = mx;
        ps[i][r] = 0.f;
      }
    // P = exp(S - m), write to LDS (swizzled), accumulate row sums
#pragma unroll
    for (int i = 0; i < 2; ++i)
#pragma unroll
      for (int j = 0; j < 4; ++j)
#pragma unroll
        for (int r = 0; r < 4; ++r) {
          float sv = mk[j] ? s_acc[i][j][r] : -__builtin_inff();
          float p = (sv == -__builtin_inff()) ? 0.f : __expf(sv - mnew[i][r]);
          ps[i][r] += p;
          QP[sw(w * 32 + i * 16 + lr * 4 + r, j * 16 + lc)] = f2bf(p);
        }
#pragma unroll
    for (int i = 0; i < 2; ++i)
#pragma unroll
      for (int r = 0; r < 4; ++r) {
        float s = ps[i][r];
        for (int d = 1; d < 16; d <<= 1) s += __shfl_xor(s, d, 64);
        l_st[i][r] = l_st[i][r] * sc[i][r] + s;
      }
#pragma unroll
    for (int i = 0; i < 2; ++i)
#pragma unroll
      for (int j = 0; j < 4; ++j)
#pragma unroll
        for (int r = 0; r < 4; ++r) acc_o[i][j][r] *= sc[i][r];
    __syncthreads();

    // O += P V
#pragma unroll
    for (int s = 0; s < 2; ++s) {
      short8 pf[2], vf[4];
#pragma unroll
      for (int i = 0; i < 2; ++i)
        pf[i] = *reinterpret_cast<const short8*>(
            &QP[sw(w * 32 + i * 16 + lc, s * 32 + lr * 8)]);
#pragma unroll
      for (int j = 0; j < 4; ++j)
        vf[j] = *reinterpret_cast<const short8*>(
            &VT[sw(j * 16 + lc, s * 32 + lr * 8)]);
#pragma unroll
      for (int i = 0; i < 2; ++i)
#pragma unroll
        for (int j = 0; j < 4; ++j)
          acc_o[i][j] =
              __builtin_amdgcn_mfma_f32_16x16x32_bf16(pf[i], vf[j], acc_o[i][j], 0, 0, 0);
    }
    __syncthreads();
  }

  // epilogue: O / l, bf16, [B, Q, D] layout for the output projection
#pragma unroll
  for (int i = 0; i < 2; ++i)
#pragma unroll
    for (int j = 0; j < 4; ++j)
#pragma unroll
      for (int r = 0; r < 4; ++r) {
        int row = qbase + w * 32 + i * 16 + lr * 4 + r;
        int d = j * 16 + lc;
        float ov = acc_o[i][j][r] / l_st[i][r];
        O[(size_t)(b * SEQ_L + row) * DMODEL + h * HD + d] = f2bf(ov);
      }
}

// ---------------- launch ----------------------------------------------------
extern "C" void kernel_launch(void* const* d_in, const int* in_sizes, int n_in,
                              void* d_out, int out_size, void* d_ws, size_t ws_size,
                              hipStream_t stream) {
  (void)in_sizes; (void)n_in; (void)out_size; (void)ws_size;
  const float* x  = (const float*)d_in[0];
  const float* y  = (const float*)d_in[1];
  const int* mask = (const int*)d_in[2];
  const float* Wq = (const float*)d_in[3];
  const float* bq = (const float*)d_in[4];
  const float* Wk = (const float*)d_in[5];
  const float* bk = (const float*)d_in[6];
  const float* Wv = (const float*)d_in[7];
  const float* bv = (const float*)d_in[8];
  const float* Wo = (const float*)d_in[9];
  const float* bo = (const float*)d_in[10];
  float* out = (float*)d_out;

  const size_t MQ = (size_t)NB * SEQ_L;          // 8192
  const size_t TOK = MQ * DMODEL;                // 8.39M elems
  const size_t TOKB = TOK * 2;                   // bytes per bf16 token tensor
  const size_t WB = (size_t)DMODEL * DMODEL * 2; // bytes per bf16 weight

  char* ws = (char*)d_ws;
  short* xb  = (short*)ws;            ws += TOKB;   // also reused for attn out
  short* yb  = (short*)ws;            ws += TOKB;
  short* wqb = (short*)ws;            ws += WB;
  short* wkb = (short*)ws;            ws += WB;
  short* wvb = (short*)ws;            ws += WB;
  short* wob = (short*)ws;            ws += WB;
  short* qh  = (short*)ws;            ws += TOKB;
  short* kh  = (short*)ws;            ws += TOKB;
  short* vh  = (short*)ws;            ws += TOKB;
  short* attnb = xb;                  // alias: xb dead after q projection

  const int W2 = DMODEL * DMODEL;
  f32_to_bf16_kernel<<<dim3((unsigned)(TOK / 1024)), 256, 0, stream>>>(x, xb, (int)TOK);
  f32_to_bf16_kernel<<<dim3((unsigned)(TOK / 1024)), 256, 0, stream>>>(y, yb, (int)TOK);
  f32_to_bf16_kernel<<<dim3(W2 / 1024), 256, 0, stream>>>(Wq, wqb, W2);
  f32_to_bf16_kernel<<<dim3(W2 / 1024), 256, 0, stream>>>(Wk, wkb, W2);
  f32_to_bf16_kernel<<<dim3(W2 / 1024), 256, 0, stream>>>(Wv, wvb, W2);
  f32_to_bf16_kernel<<<dim3(W2 / 1024), 256, 0, stream>>>(Wo, wob, W2);

  dim3 ggrid(64, 8);  // M/128, N/128
  const float qscale = 0.125f;  // 1/sqrt(64)
  gemm_bt<0><<<ggrid, 256, 0, stream>>>(xb, wqb, bq, qh, DMODEL, qscale);
  gemm_bt<0><<<ggrid, 256, 0, stream>>>(yb, wkb, bk, kh, DMODEL, 1.0f);
  gemm_bt<0><<<ggrid, 256, 0, stream>>>(yb, wvb, bv, vh, DMODEL, 1.0f);

  attn_fwd<<<dim3(16, 64), 256, 0, stream>>>(qh, kh, vh, mask, attnb);

  gemm_bt<1><<<ggrid, 256, 0, stream>>>(attnb, wob, bo, out, DMODEL, 1.0f);
}

// Round 2
// 424.399 us; speedup vs baseline: 1.5482x; 1.5482x over previous
//
#include <hip/hip_runtime.h>
#include <hip/hip_bf16.h>
#include <stdint.h>

typedef __attribute__((ext_vector_type(8))) short short8;
typedef __attribute__((ext_vector_type(4))) float f32x4;
typedef __attribute__((ext_vector_type(4))) unsigned short us4;

#define SEQ_L 2048
#define NHEADS 16
#define HD 64
#define DMODEL 1024
#define NB 4

__device__ __forceinline__ short f2bf(float f) {
  unsigned int x = __float_as_uint(f);
  x += 0x7fffu + ((x >> 16) & 1u);   // RNE
  return (short)(x >> 16);
}

__device__ __forceinline__ void gload16(const void* g, void* l) {
  __builtin_amdgcn_global_load_lds(
      (const __attribute__((address_space(1))) unsigned char*)g,
      (__attribute__((address_space(3))) unsigned char*)l, 16, 0, 0);
}

// ---------------- fp32 -> bf16 conversion (memory-bound, vectorized) --------
__global__ void f32_to_bf16_kernel(const float* __restrict__ src,
                                   short* __restrict__ dst, int n) {
  int i = (blockIdx.x * 256 + threadIdx.x) * 4;
  if (i >= n) return;
  float4 f = *reinterpret_cast<const float4*>(src + i);
  us4 o;
  o[0] = (unsigned short)f2bf(f.x);
  o[1] = (unsigned short)f2bf(f.y);
  o[2] = (unsigned short)f2bf(f.z);
  o[3] = (unsigned short)f2bf(f.w);
  *reinterpret_cast<us4*>(dst + i) = o;
}

// ---------------- GEMM: C[M,N] = A[M,K] * W[N,K]^T  (both K-major) ----------
// m97 structure: 128x128 tile, BK=32, 4 waves (2x2), global_load_lds w=16,
// double-buffered LDS, 2-phase.
template <int EPI>
__global__ void gemm_bt(const short* __restrict__ A, const short* __restrict__ W,
                        const float* __restrict__ bias, void* __restrict__ Cout,
                        int K, float oscale) {
  const int tid = threadIdx.x;
  const int w = tid >> 6, l = tid & 63;
  const int tm = blockIdx.x * 128;
  const int tn = blockIdx.y * 128;
  const int wm = (w >> 1) * 64, wn = (w & 1) * 64;
  __shared__ short As[2][128 * 32];
  __shared__ short Bs[2][128 * 32];

  const int srow = w * 32 + (l >> 2);
  const int scol = (l & 3) * 8;
  const short* pa0 = A + (size_t)(tm + srow) * K + scol;
  const short* pa1 = pa0 + (size_t)16 * K;
  const short* pb0 = W + (size_t)(tn + srow) * K + scol;
  const short* pb1 = pb0 + (size_t)16 * K;
  const int ldst = w * 1024 + l * 8;

  gload16(pa0, &As[0][ldst]);
  gload16(pa1, &As[0][ldst + 512]);
  gload16(pb0, &Bs[0][ldst]);
  gload16(pb1, &Bs[0][ldst + 512]);

  f32x4 acc[4][4];
#pragma unroll
  for (int i = 0; i < 4; ++i)
#pragma unroll
    for (int j = 0; j < 4; ++j) acc[i][j] = (f32x4){0.f, 0.f, 0.f, 0.f};

  const int lr = l >> 4, lc = l & 15;
  const int nt = K / 32;
  int cur = 0;
  __syncthreads();
  for (int t = 0; t < nt; ++t) {
    if (t + 1 < nt) {
      int ko = (t + 1) * 32;
      gload16(pa0 + ko, &As[cur ^ 1][ldst]);
      gload16(pa1 + ko, &As[cur ^ 1][ldst + 512]);
      gload16(pb0 + ko, &Bs[cur ^ 1][ldst]);
      gload16(pb1 + ko, &Bs[cur ^ 1][ldst + 512]);
    }
    short8 af[4], bfv[4];
#pragma unroll
    for (int i = 0; i < 4; ++i)
      af[i] = *reinterpret_cast<const short8*>(
          &As[cur][(wm + i * 16 + lc) * 32 + lr * 8]);
#pragma unroll
    for (int j = 0; j < 4; ++j)
      bfv[j] = *reinterpret_cast<const short8*>(
          &Bs[cur][(wn + j * 16 + lc) * 32 + lr * 8]);
#pragma unroll
    for (int i = 0; i < 4; ++i)
#pragma unroll
      for (int j = 0; j < 4; ++j)
        acc[i][j] =
            __builtin_amdgcn_mfma_f32_16x16x32_bf16(af[i], bfv[j], acc[i][j], 0, 0, 0);
    __syncthreads();
    cur ^= 1;
  }

  if (EPI == 0) {
    short* O = (short*)Cout;
#pragma unroll
    for (int j = 0; j < 4; ++j) {
      int col = tn + wn + j * 16 + lc;
      float bv = bias[col];
      int h = col >> 6, d = col & 63;
#pragma unroll
      for (int i = 0; i < 4; ++i)
#pragma unroll
        for (int r = 0; r < 4; ++r) {
          int row = tm + wm + i * 16 + lr * 4 + r;
          int b = row >> 11, pos = row & 2047;
          float v = (acc[i][j][r] + bv) * oscale;
          O[(((size_t)(b * NHEADS + h) * SEQ_L + pos) << 6) + d] = f2bf(v);
        }
    }
  } else {
    float* O = (float*)Cout;
#pragma unroll
    for (int j = 0; j < 4; ++j) {
      int col = tn + wn + j * 16 + lc;
      float bv = bias[col];
#pragma unroll
      for (int i = 0; i < 4; ++i)
#pragma unroll
        for (int r = 0; r < 4; ++r) {
          int row = tm + wm + i * 16 + lr * 4 + r;
          O[(size_t)row * DMODEL + col] = acc[i][j][r] + bv;
        }
    }
  }
}

// ---------------- flash attention -------------------------------------------
// 1D grid 1024 with XCD swizzle: all 16 q-tiles of a (b,h) -> same XCD so the
// shared K/V stream lives in one L2. 4 waves, QBLK=128, KBLK=64.
// Double-buffered K/V, ONE barrier per iteration; K prefetch via
// global_load_lds, V prefetch into regs (write-late, T14).
__global__ __launch_bounds__(256, 3) void attn_fwd(
    const short* __restrict__ Qh, const short* __restrict__ Kh,
    const short* __restrict__ Vh, const int* __restrict__ mask,
    short* __restrict__ O) {
  const int tid = threadIdx.x;
  const int w = tid >> 6, l = tid & 63;
  const int bid = blockIdx.x;
  const int bh = (bid & 7) | ((bid >> 7) << 3);  // bid%8 == bh%8 -> XCD-stable
  const int qt = (bid >> 3) & 15;
  const int b = bh >> 4, h = bh & 15;
  const short* q = Qh + (size_t)bh * SEQ_L * HD;
  const short* k = Kh + (size_t)bh * SEQ_L * HD;
  const short* v = Vh + (size_t)bh * SEQ_L * HD;
  const int* mrow = mask + b * SEQ_L;
  const int qbase = qt * 128;

  __shared__ short QP[128 * 64];   // Q staging, then P tile
  __shared__ short KT[2][64 * 64];
  __shared__ short VT[2][64 * 64]; // V^T : [d][k]

  auto sw = [](int row, int e) { return row * 64 + (e ^ ((row & 7) << 3)); };

  // stage Q via global_load_lds: linear dest, inverse-swizzled source
#pragma unroll
  for (int qi = 0; qi < 4; ++qi) {
    int c = w * 4 + qi;
    int row = c * 8 + (l >> 3);
    int ss = (l & 7) ^ (l >> 3);
    gload16(q + (size_t)(qbase + row) * HD + ss * 8, &QP[c * 512 + l * 8]);
  }

  const int lr = l >> 4, lc = l & 15;

  short8 va, vb;
  auto stageK = [&](int kb, int buf) {
#pragma unroll
    for (int qi = 0; qi < 2; ++qi) {
      int c = w * 2 + qi;
      int row = c * 8 + (l >> 3);
      int ss = (l & 7) ^ (l >> 3);
      gload16(k + (size_t)(kb + row) * HD + ss * 8, &KT[buf][c * 512 + l * 8]);
    }
  };
  auto loadV = [&](int kb) {
    const short* vp = v + (size_t)(kb + l) * HD + w * 16;
    va = *reinterpret_cast<const short8*>(vp);
    vb = *reinterpret_cast<const short8*>(vp + 8);
  };
  auto writeV = [&](int buf) {
#pragma unroll
    for (int e = 0; e < 8; ++e) {
      VT[buf][sw(w * 16 + e, l)] = va[e];
      VT[buf][sw(w * 16 + 8 + e, l)] = vb[e];
    }
  };

  // prologue: chunk 0 into buf 0 (Q gloads also drain at this barrier)
  stageK(0, 0);
  loadV(0);
  writeV(0);
  __syncthreads();

  short8 qf[2][2];
#pragma unroll
  for (int i = 0; i < 2; ++i)
#pragma unroll
    for (int s = 0; s < 2; ++s)
      qf[i][s] = *reinterpret_cast<const short8*>(
          &QP[sw(w * 32 + i * 16 + lc, s * 32 + lr * 8)]);

  float m_st[2][4], l_st[2][4];
  f32x4 acc_o[2][4];
#pragma unroll
  for (int i = 0; i < 2; ++i)
#pragma unroll
    for (int r = 0; r < 4; ++r) { m_st[i][r] = -3.0e38f; l_st[i][r] = 0.f; }
#pragma unroll
  for (int i = 0; i < 2; ++i)
#pragma unroll
    for (int j = 0; j < 4; ++j) acc_o[i][j] = (f32x4){0.f, 0.f, 0.f, 0.f};

  int cur = 0;
  const int NT = SEQ_L / 64;
  for (int ic = 0; ic < NT; ++ic) {
    const int kb = ic * 64;
    const bool pf = (ic + 1 < NT);
    if (pf) {                       // prefetch next chunk (issue-early)
      stageK(kb + 64, cur ^ 1);
      loadV(kb + 64);
    }

    float mb[4];
#pragma unroll
    for (int j = 0; j < 4; ++j)
      mb[j] = mrow[kb + j * 16 + lc] ? 0.f : -__builtin_inff();

    // S = Q K^T (1/sqrt(hd) folded into Q) + mask bias
    f32x4 s_acc[2][4];
#pragma unroll
    for (int i = 0; i < 2; ++i)
#pragma unroll
      for (int j = 0; j < 4; ++j) s_acc[i][j] = (f32x4){0.f, 0.f, 0.f, 0.f};
#pragma unroll
    for (int s = 0; s < 2; ++s) {
      short8 kf[4];
#pragma unroll
      for (int j = 0; j < 4; ++j)
        kf[j] = *reinterpret_cast<const short8*>(
            &KT[cur][sw(j * 16 + lc, s * 32 + lr * 8)]);
#pragma unroll
      for (int i = 0; i < 2; ++i)
#pragma unroll
        for (int j = 0; j < 4; ++j)
          s_acc[i][j] =
              __builtin_amdgcn_mfma_f32_16x16x32_bf16(qf[i][s], kf[j], s_acc[i][j], 0, 0, 0);
    }
#pragma unroll
    for (int i = 0; i < 2; ++i)
#pragma unroll
      for (int j = 0; j < 4; ++j)
#pragma unroll
        for (int r = 0; r < 4; ++r) s_acc[i][j][r] += mb[j];

    // online softmax (rows live in 16-lane groups)
    float mnew[2][4], sc[2][4], ps[2][4];
#pragma unroll
    for (int i = 0; i < 2; ++i)
#pragma unroll
      for (int r = 0; r < 4; ++r) {
        float mx = fmaxf(fmaxf(s_acc[i][0][r], s_acc[i][1][r]),
                         fmaxf(s_acc[i][2][r], s_acc[i][3][r]));
        for (int d = 1; d < 16; d <<= 1) mx = fmaxf(mx, __shfl_xor(mx, d, 64));
        mx = fmaxf(mx, m_st[i][r]);
        sc[i][r] = (m_st[i][r] == mx) ? 1.f : __expf(m_st[i][r] - mx);
        mnew[i][r] = mx;
        m_st[i][r] = mx;
        ps[i][r] = 0.f;
      }
    // P = exp(S - m) (masked entries are -inf -> exp gives 0), write swizzled
#pragma unroll
    for (int i = 0; i < 2; ++i)
#pragma unroll
      for (int j = 0; j < 4; ++j)
#pragma unroll
        for (int r = 0; r < 4; ++r) {
          float p = __expf(s_acc[i][j][r] - mnew[i][r]);
          ps[i][r] += p;
          QP[sw(w * 32 + i * 16 + lr * 4 + r, j * 16 + lc)] = f2bf(p);
        }
#pragma unroll
    for (int i = 0; i < 2; ++i)
#pragma unroll
      for (int r = 0; r < 4; ++r) {
        float s = ps[i][r];
        for (int d = 1; d < 16; d <<= 1) s += __shfl_xor(s, d, 64);
        l_st[i][r] = l_st[i][r] * sc[i][r] + s;
      }
#pragma unroll
    for (int i = 0; i < 2; ++i)
#pragma unroll
      for (int j = 0; j < 4; ++j)
#pragma unroll
        for (int r = 0; r < 4; ++r) acc_o[i][j][r] *= sc[i][r];

    // O += P V   (P rows are this wave's own -> no barrier needed before read)
#pragma unroll
    for (int s = 0; s < 2; ++s) {
      short8 pf2[2], vf[4];
#pragma unroll
      for (int i = 0; i < 2; ++i)
        pf2[i] = *reinterpret_cast<const short8*>(
            &QP[sw(w * 32 + i * 16 + lc, s * 32 + lr * 8)]);
#pragma unroll
      for (int j = 0; j < 4; ++j)
        vf[j] = *reinterpret_cast<const short8*>(
            &VT[cur][sw(j * 16 + lc, s * 32 + lr * 8)]);
#pragma unroll
      for (int i = 0; i < 2; ++i)
#pragma unroll
        for (int j = 0; j < 4; ++j)
          acc_o[i][j] =
              __builtin_amdgcn_mfma_f32_16x16x32_bf16(pf2[i], vf[j], acc_o[i][j], 0, 0, 0);
    }

    if (pf) writeV(cur ^ 1);  // write-late: V regs -> next buffer
    __syncthreads();          // drains K gloads + V ds_writes; flips buffers
    cur ^= 1;
  }

  // epilogue: O / l, bf16, [B, Q, D] layout for the output projection
#pragma unroll
  for (int i = 0; i < 2; ++i)
#pragma unroll
    for (int j = 0; j < 4; ++j)
#pragma unroll
      for (int r = 0; r < 4; ++r) {
        int row = qbase + w * 32 + i * 16 + lr * 4 + r;
        int d = j * 16 + lc;
        float ov = acc_o[i][j][r] / l_st[i][r];
        O[(size_t)(b * SEQ_L + row) * DMODEL + h * HD + d] = f2bf(ov);
      }
}

// ---------------- launch ----------------------------------------------------
extern "C" void kernel_launch(void* const* d_in, const int* in_sizes, int n_in,
                              void* d_out, int out_size, void* d_ws, size_t ws_size,
                              hipStream_t stream) {
  (void)in_sizes; (void)n_in; (void)out_size; (void)ws_size;
  const float* x  = (const float*)d_in[0];
  const float* y  = (const float*)d_in[1];
  const int* mask = (const int*)d_in[2];
  const float* Wq = (const float*)d_in[3];
  const float* bq = (const float*)d_in[4];
  const float* Wk = (const float*)d_in[5];
  const float* bk = (const float*)d_in[6];
  const float* Wv = (const float*)d_in[7];
  const float* bv = (const float*)d_in[8];
  const float* Wo = (const float*)d_in[9];
  const float* bo = (const float*)d_in[10];
  float* out = (float*)d_out;

  const size_t MQ = (size_t)NB * SEQ_L;
  const size_t TOK = MQ * DMODEL;
  const size_t TOKB = TOK * 2;
  const size_t WB = (size_t)DMODEL * DMODEL * 2;

  char* ws = (char*)d_ws;
  short* xb  = (short*)ws;            ws += TOKB;
  short* yb  = (short*)ws;            ws += TOKB;
  short* wqb = (short*)ws;            ws += WB;
  short* wkb = (short*)ws;            ws += WB;
  short* wvb = (short*)ws;            ws += WB;
  short* wob = (short*)ws;            ws += WB;
  short* qh  = (short*)ws;            ws += TOKB;
  short* kh  = (short*)ws;            ws += TOKB;
  short* vh  = (short*)ws;            ws += TOKB;
  short* attnb = xb;                  // alias: xb dead after q projection

  const int W2 = DMODEL * DMODEL;
  f32_to_bf16_kernel<<<dim3((unsigned)(TOK / 1024)), 256, 0, stream>>>(x, xb, (int)TOK);
  f32_to_bf16_kernel<<<dim3((unsigned)(TOK / 1024)), 256, 0, stream>>>(y, yb, (int)TOK);
  f32_to_bf16_kernel<<<dim3(W2 / 1024), 256, 0, stream>>>(Wq, wqb, W2);
  f32_to_bf16_kernel<<<dim3(W2 / 1024), 256, 0, stream>>>(Wk, wkb, W2);
  f32_to_bf16_kernel<<<dim3(W2 / 1024), 256, 0, stream>>>(Wv, wvb, W2);
  f32_to_bf16_kernel<<<dim3(W2 / 1024), 256, 0, stream>>>(Wo, wob, W2);

  dim3 ggrid(64, 8);
  const float qscale = 0.125f;  // 1/sqrt(64)
  gemm_bt<0><<<ggrid, 256, 0, stream>>>(xb, wqb, bq, qh, DMODEL, qscale);
  gemm_bt<0><<<ggrid, 256, 0, stream>>>(yb, wkb, bk, kh, DMODEL, 1.0f);
  gemm_bt<0><<<ggrid, 256, 0, stream>>>(yb, wvb, bv, vh, DMODEL, 1.0f);

  attn_fwd<<<dim3(1024), 256, 0, stream>>>(qh, kh, vh, mask, attnb);

  gemm_bt<1><<<ggrid, 256, 0, stream>>>(attnb, wob, bo, out, DMODEL, 1.0f);
}